// Round 1
// baseline (559.132 us; speedup 1.0000x reference)
//
#include <hip/hip_runtime.h>
#include <hip/hip_bf16.h>
#include <math.h>

#define SEQ_LEN 8192
#define LAT 64
#define NPOS 8256          // SEQ_LEN + LAT
#define NBATCH 16
#define NHEADS 8
#define DH 64
#define DIM 512
#define NBH 128            // NBATCH*NHEADS
#define NROWS 132096       // NBATCH*NPOS
#define NCHUNK 4
#define NTILES 129         // NPOS/64

typedef unsigned short u16;
typedef unsigned int   u32;
using short8 = __attribute__((ext_vector_type(8))) short;  // MFMA bf16 A/B frag (guide §3)
using f32x4  = __attribute__((ext_vector_type(4))) float;  // MFMA C/D frag

static __device__ __forceinline__ float bf2f(u16 u) {
  union { u32 i; float f; } v; v.i = ((u32)u) << 16; return v.f;
}
static __device__ __forceinline__ u16 f2bf(float f) {  // round-to-nearest-even
  union { float f; u32 i; } v; v.f = f;
  u32 x = v.i;
  return (u16)((x + 0x7fffu + ((x >> 16) & 1u)) >> 16);
}

// ---------------- kernel 0: rope tables (cos/sin per (pos, i<32)) ----------------
__global__ void k_rtable(float* __restrict__ ctab, float* __restrict__ stab) {
  int idx = blockIdx.x * 256 + threadIdx.x;   // NPOS*32 total
  int pos = idx >> 5, i = idx & 31;
  float inv = (float)(1.0 / pow(10000.0, (double)(2 * i) / 64.0));
  float ang = (float)pos * inv;               // f32 product, like jnp
  ctab[idx] = cosf(ang);
  stab[idx] = sinf(ang);
}

// ---------------- kernel 1: q projection (latent rows only) + rope + scale ----------------
// 128 blocks x 8 latent rows. q[m][nn] = sum_k x[m][k]*wq[nn][k], f32 exact, then rope, *0.125, bf16.
__global__ __launch_bounds__(256) void k_qproj(
    const float* __restrict__ x, const float* __restrict__ wq,
    const float* __restrict__ ctab, const float* __restrict__ stab,
    u16* __restrict__ qws) {
  __shared__ __align__(16) float xs[8 * 512];
  int t = threadIdx.x;
  int lr0 = blockIdx.x * 8;
  int batch = lr0 >> 6;
  int lat0 = lr0 & 63;
  for (int u = 0; u < 4; ++u) {               // stage 8 rows of x (1024 float4)
    int e = u * 256 + t;
    int row = e >> 7, c4 = e & 127;
    size_t m = (size_t)batch * NPOS + SEQ_LEN + lat0 + row;
    ((float4*)xs)[e] = ((const float4*)(x + m * DIM))[c4];
  }
  __syncthreads();
  float acc0[8], acc1[8];
#pragma unroll
  for (int r = 0; r < 8; ++r) { acc0[r] = 0.f; acc1[r] = 0.f; }
  const float4* w0 = (const float4*)(wq + (size_t)t * DIM);
  const float4* w1 = (const float4*)(wq + (size_t)(t + 256) * DIM);
  for (int kk = 0; kk < 128; ++kk) {
    float4 a = w0[kk], b = w1[kk];
#pragma unroll
    for (int r = 0; r < 8; ++r) {
      float4 xv = ((const float4*)xs)[r * 128 + kk];
      acc0[r] = fmaf(a.x, xv.x, fmaf(a.y, xv.y, fmaf(a.z, xv.z, fmaf(a.w, xv.w, acc0[r]))));
      acc1[r] = fmaf(b.x, xv.x, fmaf(b.y, xv.y, fmaf(b.z, xv.z, fmaf(b.w, xv.w, acc1[r]))));
    }
  }
  __syncthreads();
#pragma unroll
  for (int r = 0; r < 8; ++r) { xs[r * 512 + t] = acc0[r]; xs[r * 512 + t + 256] = acc1[r]; }
  __syncthreads();
  int rh = t >> 2, sub = t & 3;
  int row = rh >> 3, head = rh & 7;
  int lat = lat0 + row, pos = SEQ_LEN + lat;
  int bh = batch * 8 + head;
  u16* qd = qws + ((size_t)bh * LAT + lat) * DH;
#pragma unroll
  for (int u = 0; u < 8; ++u) {
    int i = sub * 8 + u;
    float v1 = xs[row * 512 + head * 64 + i];
    float v2 = xs[row * 512 + head * 64 + i + 32];
    float cc = ctab[pos * 32 + i], ss = stab[pos * 32 + i];
    qd[i]      = f2bf((v1 * cc - v2 * ss) * 0.125f);
    qd[i + 32] = f2bf((v2 * cc + v1 * ss) * 0.125f);
  }
}

// ---------------- kernel 2: kv = x @ wkv^T (bf16 MFMA), epilogue rope+LN stats ----------------
// grid (4 n-blocks fastest, 1032 m-blocks). 128x128 tile, BK=64, 4 waves (2x2), single-buffer LDS.
__global__ __launch_bounds__(256) void k_kvgemm(
    const float* __restrict__ x, const float* __restrict__ wkv,
    const float* __restrict__ ctab, const float* __restrict__ stab,
    u16* __restrict__ kvws, float2* __restrict__ stats) {
  __shared__ __align__(16) float smem[16896];   // 67584B: {As 16K + Bs 16K} then Cs[128][132]
  u16* As = (u16*)smem;                          // [128][64] bf16, rows XOR-swizzled (T2)
  u16* Bs = As + 128 * 64;
  int t = threadIdx.x;
  int lane = t & 63, w = t >> 6;
  int wr = w >> 1, wc = w & 1;
  int c = lane & 15, g = lane >> 4;
  size_t m0 = (size_t)blockIdx.y * 128;
  int n0 = blockIdx.x * 128;
  f32x4 acc[4][4];
#pragma unroll
  for (int mt = 0; mt < 4; ++mt)
#pragma unroll
    for (int nt = 0; nt < 4; ++nt) acc[mt][nt] = (f32x4){0.f, 0.f, 0.f, 0.f};
  int ra = t >> 1, kh = t & 1;
  const float* arow = x + (m0 + ra) * DIM + kh * 32;
  const float* brow = wkv + (size_t)(n0 + ra) * DIM + kh * 32;
  char* abase = (char*)As + ra * 128;
  char* bbase = (char*)Bs + ra * 128;
  int rsw = (ra & 7) << 4;
  for (int kt = 0; kt < 8; ++kt) {
    __syncthreads();
    {
      const float4* sa = (const float4*)(arow + kt * 64);
      const float4* sb = (const float4*)(brow + kt * 64);
#pragma unroll
      for (int u = 0; u < 4; ++u) {
        float4 a0 = sa[2 * u], a1 = sa[2 * u + 1];
        short8 oa;
        oa[0] = (short)f2bf(a0.x); oa[1] = (short)f2bf(a0.y); oa[2] = (short)f2bf(a0.z); oa[3] = (short)f2bf(a0.w);
        oa[4] = (short)f2bf(a1.x); oa[5] = (short)f2bf(a1.y); oa[6] = (short)f2bf(a1.z); oa[7] = (short)f2bf(a1.w);
        *(short8*)(abase + ((kh * 64 + 16 * u) ^ rsw)) = oa;
        float4 b0 = sb[2 * u], b1 = sb[2 * u + 1];
        short8 ob;
        ob[0] = (short)f2bf(b0.x); ob[1] = (short)f2bf(b0.y); ob[2] = (short)f2bf(b0.z); ob[3] = (short)f2bf(b0.w);
        ob[4] = (short)f2bf(b1.x); ob[5] = (short)f2bf(b1.y); ob[6] = (short)f2bf(b1.z); ob[7] = (short)f2bf(b1.w);
        *(short8*)(bbase + ((kh * 64 + 16 * u) ^ rsw)) = ob;
      }
    }
    __syncthreads();
#pragma unroll
    for (int ks = 0; ks < 2; ++ks) {
      short8 am[4], bn[4];
#pragma unroll
      for (int mt = 0; mt < 4; ++mt) {
        int row = wr * 64 + mt * 16 + c;
        am[mt] = *(short8*)((char*)As + row * 128 + ((ks * 64 + 16 * g) ^ ((row & 7) << 4)));
      }
#pragma unroll
      for (int nt = 0; nt < 4; ++nt) {
        int row = wc * 64 + nt * 16 + c;
        bn[nt] = *(short8*)((char*)Bs + row * 128 + ((ks * 64 + 16 * g) ^ ((row & 7) << 4)));
      }
#pragma unroll
      for (int mt = 0; mt < 4; ++mt)
#pragma unroll
        for (int nt = 0; nt < 4; ++nt)
          acc[mt][nt] = __builtin_amdgcn_mfma_f32_16x16x32_bf16(am[mt], bn[nt], acc[mt][nt], 0, 0, 0);
    }
  }
  __syncthreads();
  float* Cs = smem;   // [128][132] f32
#pragma unroll
  for (int mt = 0; mt < 4; ++mt)
#pragma unroll
    for (int nt = 0; nt < 4; ++nt)
#pragma unroll
      for (int r = 0; r < 4; ++r)
        Cs[(wr * 64 + mt * 16 + 4 * g + r) * 132 + wc * 64 + nt * 16 + c] = acc[mt][nt][r];
  __syncthreads();
  // epilogue: thread t owns (row r_, head-half hh): rope 64 dims, LN stats, store bf16 + stats
  int r_ = t & 127, hh = t >> 7;
  float v[64];
#pragma unroll
  for (int e = 0; e < 64; ++e) v[e] = Cs[r_ * 132 + hh * 64 + e];
  int mi = (int)(m0 + r_);
  int b = mi / NPOS, pos = mi % NPOS;
  const float* ct = ctab + pos * 32;
  const float* st = stab + pos * 32;
#pragma unroll
  for (int i = 0; i < 32; ++i) {
    float cc = ct[i], ss = st[i];
    float v1 = v[i], v2 = v[i + 32];
    v[i]      = v1 * cc - v2 * ss;
    v[i + 32] = v2 * cc + v1 * ss;
  }
  float sum = 0.f;
#pragma unroll
  for (int e = 0; e < 64; ++e) sum += v[e];
  float mu = sum * 0.015625f;
  float sq = 0.f;
#pragma unroll
  for (int e = 0; e < 64; ++e) { float d = v[e] - mu; sq = fmaf(d, d, sq); }
  float rstd = rsqrtf(sq * 0.015625f + 1e-5f);
  int head = blockIdx.x * 2 + hh;
  int bh = b * 8 + head;
  u32 pk[32];
#pragma unroll
  for (int e = 0; e < 32; ++e) pk[e] = (u32)f2bf(v[2 * e]) | ((u32)f2bf(v[2 * e + 1]) << 16);
  uint4* dst = (uint4*)(kvws + ((size_t)bh * NPOS + pos) * DH);
#pragma unroll
  for (int u = 0; u < 8; ++u) dst[u] = make_uint4(pk[4 * u], pk[4 * u + 1], pk[4 * u + 2], pk[4 * u + 3]);
  stats[(size_t)bh * NPOS + pos] = make_float2(mu, rstd);
}

// ---------------- kernel 3: flash attention over j, split into 4 chunks ----------------
// grid (NCHUNK, NBH), 256 thr = 4 waves, wave w owns q rows [16w,16w+16). JT=64 (129 tiles, no tail).
__global__ __launch_bounds__(256) void k_attn(
    const u16* __restrict__ qws, const u16* __restrict__ kvws,
    const float2* __restrict__ stats, const float* __restrict__ lng, const float* __restrict__ lnb,
    float* __restrict__ pout, float* __restrict__ pml) {
  __shared__ __align__(16) u16 LT[64 * 64];        // lkv^T [dd][j], rows XOR-swizzled
  __shared__ __align__(16) u16 Pl[4][16 * 64];     // per-wave P [i][j], XOR-swizzled
  __shared__ float gl[64], bl[64];
  int t = threadIdx.x;
  int lane = t & 63, w = t >> 6;
  int c = lane & 15, g = lane >> 4;
  int bh = blockIdx.y, chunk = blockIdx.x;
  int tt0 = chunk * 33;
  int tt1 = tt0 + 33; if (tt1 > NTILES) tt1 = NTILES;
  if (t < 64) { gl[t] = lng[t]; bl[t] = lnb[t]; }
  short8 qa[2];
  {
    const u16* qrow = qws + ((size_t)bh * LAT + w * 16 + c) * DH;
    qa[0] = *(const short8*)(qrow + 8 * g);
    qa[1] = *(const short8*)(qrow + 32 + 8 * g);
  }
  f32x4 oacc[4];
#pragma unroll
  for (int nt = 0; nt < 4; ++nt) oacc[nt] = (f32x4){0.f, 0.f, 0.f, 0.f};
  float m_run[4], l_run[4];
#pragma unroll
  for (int r = 0; r < 4; ++r) { m_run[r] = -INFINITY; l_run[r] = 0.f; }
  int sj = t & 63, sw = t >> 6;
  for (int tt = tt0; tt < tt1; ++tt) {
    int j0 = tt * 64;
    __syncthreads();                                // prev PV reads of LT done (also covers gl/bl init)
    {                                               // stage LN'd kv transposed: LT[dd][j]
      const u16* src = kvws + ((size_t)bh * NPOS + j0 + sj) * DH + 16 * sw;
      short8 v0 = *(const short8*)src;
      short8 v1 = *(const short8*)(src + 8);
      float2 stv = stats[(size_t)bh * NPOS + j0 + sj];
      float A = stv.y, C = -stv.x * stv.y;
      char* ltb = (char*)LT;
#pragma unroll
      for (int e = 0; e < 16; ++e) {
        int dd = 16 * sw + e;
        u16 uv = (u16)((e < 8) ? v0[e] : v1[e - 8]);
        float y = fmaf(bf2f(uv), A, C);
        y = fmaf(y, gl[dd], bl[dd]);
        *(u16*)(ltb + dd * 128 + ((2 * sj) ^ ((dd & 7) << 4))) = f2bf(y);
      }
    }
    __syncthreads();
    // QK^T: S[i][j], A=q frags (regs), B=K^T frags direct from global (k=dd contiguous)
    f32x4 sacc[4];
#pragma unroll
    for (int jn = 0; jn < 4; ++jn) sacc[jn] = (f32x4){0.f, 0.f, 0.f, 0.f};
    const u16* kb = kvws + ((size_t)bh * NPOS + j0) * DH;
#pragma unroll
    for (int ks = 0; ks < 2; ++ks)
#pragma unroll
      for (int jn = 0; jn < 4; ++jn) {
        short8 kf = *(const short8*)(kb + (size_t)(jn * 16 + c) * DH + ks * 32 + 8 * g);
        sacc[jn] = __builtin_amdgcn_mfma_f32_16x16x32_bf16(qa[ks], kf, sacc[jn], 0, 0, 0);
      }
    // online softmax; lane holds S[i=4g+r][j=jn*16+c]
    char* pb = (char*)Pl[w];
#pragma unroll
    for (int r = 0; r < 4; ++r) {
      float mt0 = fmaxf(fmaxf(sacc[0][r], sacc[1][r]), fmaxf(sacc[2][r], sacc[3][r]));
      mt0 = fmaxf(mt0, __shfl_xor(mt0, 1));
      mt0 = fmaxf(mt0, __shfl_xor(mt0, 2));
      mt0 = fmaxf(mt0, __shfl_xor(mt0, 4));
      mt0 = fmaxf(mt0, __shfl_xor(mt0, 8));
      float mnew = fmaxf(m_run[r], mt0);
      float corr = __expf(m_run[r] - mnew);
      m_run[r] = mnew;
      float ts = 0.f;
#pragma unroll
      for (int jn = 0; jn < 4; ++jn) {
        float p = __expf(sacc[jn][r] - mnew);
        sacc[jn][r] = p;
        ts += p;
      }
      ts += __shfl_xor(ts, 1); ts += __shfl_xor(ts, 2);
      ts += __shfl_xor(ts, 4); ts += __shfl_xor(ts, 8);
      l_run[r] = l_run[r] * corr + ts;
#pragma unroll
      for (int nt = 0; nt < 4; ++nt) oacc[nt][r] *= corr;
      int i = 4 * g + r;
      int isw = (i & 7) << 4;
#pragma unroll
      for (int jn = 0; jn < 4; ++jn) {
        int j = jn * 16 + c;
        *(u16*)(pb + i * 128 + ((2 * j) ^ isw)) = f2bf(sacc[jn][r]);
      }
    }
    // PV: out[i][dd] += P @ LKV (wave-local P round-trip, DS ops in-order per wave)
#pragma unroll
    for (int ks = 0; ks < 2; ++ks) {
      short8 pa = *(const short8*)(pb + c * 128 + ((ks * 64 + 16 * g) ^ ((c & 7) << 4)));
#pragma unroll
      for (int nt = 0; nt < 4; ++nt) {
        int dd = nt * 16 + c;
        short8 lv = *(const short8*)((char*)LT + dd * 128 + ((ks * 64 + 16 * g) ^ ((dd & 7) << 4)));
        oacc[nt] = __builtin_amdgcn_mfma_f32_16x16x32_bf16(pa, lv, oacc[nt], 0, 0, 0);
      }
    }
  }
  size_t ob = (size_t)bh * NCHUNK + chunk;
#pragma unroll
  for (int nt = 0; nt < 4; ++nt)
#pragma unroll
    for (int r = 0; r < 4; ++r) {
      int i = w * 16 + 4 * g + r;
      pout[(ob * 64 + i) * 64 + nt * 16 + c] = oacc[nt][r];
    }
  if (c == 0) {
#pragma unroll
    for (int r = 0; r < 4; ++r) {
      int i = w * 16 + 4 * g + r;
      pml[(ob * 2 + 0) * 64 + i] = m_run[r];
      pml[(ob * 2 + 1) * 64 + i] = l_run[r];
    }
  }
}

// ---------------- kernel 4: combine split-k partials, normalize, permute to output ----------------
__global__ __launch_bounds__(256) void k_combine(
    const float* __restrict__ pout, const float* __restrict__ pml, float* __restrict__ out) {
  int bh = blockIdx.x, t = threadIdx.x;
  int i = t >> 2, dq = t & 3;
  float mv[NCHUNK], lv[NCHUNK];
#pragma unroll
  for (int cc = 0; cc < NCHUNK; ++cc) {
    size_t ob = (size_t)bh * NCHUNK + cc;
    mv[cc] = pml[(ob * 2 + 0) * 64 + i];
    lv[cc] = pml[(ob * 2 + 1) * 64 + i];
  }
  float M = fmaxf(fmaxf(mv[0], mv[1]), fmaxf(mv[2], mv[3]));
  float wsum = 0.f, wcf[NCHUNK];
#pragma unroll
  for (int cc = 0; cc < NCHUNK; ++cc) { wcf[cc] = __expf(mv[cc] - M); wsum = fmaf(wcf[cc], lv[cc], wsum); }
  float inv = 1.0f / wsum;
#pragma unroll
  for (int e = 0; e < 16; ++e) {
    int dd = dq * 16 + e;
    float a = 0.f;
#pragma unroll
    for (int cc = 0; cc < NCHUNK; ++cc)
      a = fmaf(wcf[cc], pout[(((size_t)bh * NCHUNK + cc) * 64 + i) * 64 + dd], a);
    out[((size_t)(bh >> 3) * LAT + i) * DIM + (bh & 7) * DH + dd] = a * inv;
  }
}

extern "C" void kernel_launch(void* const* d_in, const int* in_sizes, int n_in,
                              void* d_out, int out_size, void* d_ws, size_t ws_size,
                              hipStream_t stream) {
  const float* x   = (const float*)d_in[0];
  const float* wq  = (const float*)d_in[1];
  const float* wkv = (const float*)d_in[2];
  const float* lng = (const float*)d_in[3];
  const float* lnb = (const float*)d_in[4];
  float* out = (float*)d_out;
  char* ws = (char*)d_ws;
  size_t off = 0;
  auto alloc = [&](size_t bytes) { char* p = ws + off; off += (bytes + 255) & ~(size_t)255; return p; };
  float*  ctab  = (float*)alloc((size_t)NPOS * 32 * 4);                 // 1.06 MB
  float*  stab  = (float*)alloc((size_t)NPOS * 32 * 4);                 // 1.06 MB
  u16*    qws   = (u16*)alloc((size_t)NBH * LAT * DH * 2);              // 1 MB
  u16*    kvws  = (u16*)alloc((size_t)NBH * NPOS * DH * 2);             // 135.3 MB
  float2* stats = (float2*)alloc((size_t)NBH * NPOS * 8);               // 8.45 MB
  float*  pout  = (float*)alloc((size_t)NBH * NCHUNK * 64 * 64 * 4);    // 8.39 MB
  float*  pml   = (float*)alloc((size_t)NBH * NCHUNK * 2 * 64 * 4);     // 0.26 MB
  (void)in_sizes; (void)n_in; (void)out_size; (void)ws_size;            // total ~156 MB

  hipLaunchKernelGGL(k_rtable, dim3(NPOS * 32 / 256), dim3(256), 0, stream, ctab, stab);
  hipLaunchKernelGGL(k_qproj, dim3(128), dim3(256), 0, stream, x, wq, ctab, stab, qws);
  hipLaunchKernelGGL(k_kvgemm, dim3(4, 1032), dim3(256), 0, stream, x, wkv, ctab, stab, kvws, stats);
  hipLaunchKernelGGL(k_attn, dim3(NCHUNK, NBH), dim3(256), 0, stream, qws, kvws, stats, lng, lnb, pout, pml);
  hipLaunchKernelGGL(k_combine, dim3(NBH), dim3(256), 0, stream, pout, pml, out);
}

// Round 2
// 531.809 us; speedup vs baseline: 1.0514x; 1.0514x over previous
//
#include <hip/hip_runtime.h>
#include <hip/hip_bf16.h>
#include <math.h>

#define SEQ_LEN 8192
#define LAT 64
#define NPOS 8256          // SEQ_LEN + LAT
#define NBATCH 16
#define NHEADS 8
#define DH 64
#define DIM 512
#define NBH 128            // NBATCH*NHEADS
#define NROWS 132096       // NBATCH*NPOS
#define NCHUNK 4
#define NTILES 129         // NPOS/64

typedef unsigned short u16;
typedef unsigned int   u32;
using short8 = __attribute__((ext_vector_type(8))) short;  // MFMA bf16 A/B frag
using f32x4  = __attribute__((ext_vector_type(4))) float;  // MFMA C/D frag

static __device__ __forceinline__ float bf2f(u16 u) {
  union { u32 i; float f; } v; v.i = ((u32)u) << 16; return v.f;
}
static __device__ __forceinline__ u16 f2bf(float f) {  // round-to-nearest-even
  union { float f; u32 i; } v; v.f = f;
  u32 x = v.i;
  return (u16)((x + 0x7fffu + ((x >> 16) & 1u)) >> 16);
}
static __device__ __forceinline__ void gload_lds16(const void* g, void* l) {
  // async global->LDS, 16B per lane (guide §5; LDS dest = wave-uniform base + lane*16)
  __builtin_amdgcn_global_load_lds(
      (const __attribute__((address_space(1))) unsigned int*)g,
      (__attribute__((address_space(3))) unsigned int*)l, 16, 0, 0);
}

// ---------------- kernel 0: rope tables (cos/sin per (pos, i<32)) ----------------
__global__ void k_rtable(float* __restrict__ ctab, float* __restrict__ stab) {
  int idx = blockIdx.x * 256 + threadIdx.x;   // NPOS*32 total
  int pos = idx >> 5, i = idx & 31;
  float inv = (float)(1.0 / pow(10000.0, (double)(2 * i) / 64.0));
  float ang = (float)pos * inv;               // f32 product, like jnp
  ctab[idx] = cosf(ang);
  stab[idx] = sinf(ang);
}

// ---------------- kernel 0b: cast x and wkv to bf16 (vectorized, memory-bound) ----------------
__global__ __launch_bounds__(256) void k_xcast(
    const float* __restrict__ x, const float* __restrict__ wkv,
    u16* __restrict__ xbf, u16* __restrict__ wbf) {
  const size_t NX8 = (size_t)NROWS * DIM / 8;   // 8,454,144 groups of 8
  const size_t NW8 = (size_t)DIM * DIM / 8;     // 32,768
  size_t total = NX8 + NW8;
  for (size_t i = (size_t)blockIdx.x * 256 + threadIdx.x; i < total;
       i += (size_t)gridDim.x * 256) {
    const float4* src; u32* dst; size_t k;
    if (i < NX8) { src = (const float4*)x;   dst = (u32*)xbf; k = i; }
    else         { src = (const float4*)wkv; dst = (u32*)wbf; k = i - NX8; }
    float4 a = src[2 * k], b = src[2 * k + 1];
    uint4 o;
    o.x = (u32)f2bf(a.x) | ((u32)f2bf(a.y) << 16);
    o.y = (u32)f2bf(a.z) | ((u32)f2bf(a.w) << 16);
    o.z = (u32)f2bf(b.x) | ((u32)f2bf(b.y) << 16);
    o.w = (u32)f2bf(b.z) | ((u32)f2bf(b.w) << 16);
    ((uint4*)dst)[k] = o;
  }
}

// ---------------- kernel 1: q projection (latent rows only) + rope + scale ----------------
__global__ __launch_bounds__(256) void k_qproj(
    const float* __restrict__ x, const float* __restrict__ wq,
    const float* __restrict__ ctab, const float* __restrict__ stab,
    u16* __restrict__ qws) {
  __shared__ __align__(16) float xs[8 * 512];
  int t = threadIdx.x;
  int lr0 = blockIdx.x * 8;
  int batch = lr0 >> 6;
  int lat0 = lr0 & 63;
  for (int u = 0; u < 4; ++u) {               // stage 8 rows of x (1024 float4)
    int e = u * 256 + t;
    int row = e >> 7, c4 = e & 127;
    size_t m = (size_t)batch * NPOS + SEQ_LEN + lat0 + row;
    ((float4*)xs)[e] = ((const float4*)(x + m * DIM))[c4];
  }
  __syncthreads();
  float acc0[8], acc1[8];
#pragma unroll
  for (int r = 0; r < 8; ++r) { acc0[r] = 0.f; acc1[r] = 0.f; }
  const float4* w0 = (const float4*)(wq + (size_t)t * DIM);
  const float4* w1 = (const float4*)(wq + (size_t)(t + 256) * DIM);
  for (int kk = 0; kk < 128; ++kk) {
    float4 a = w0[kk], b = w1[kk];
#pragma unroll
    for (int r = 0; r < 8; ++r) {
      float4 xv = ((const float4*)xs)[r * 128 + kk];
      acc0[r] = fmaf(a.x, xv.x, fmaf(a.y, xv.y, fmaf(a.z, xv.z, fmaf(a.w, xv.w, acc0[r]))));
      acc1[r] = fmaf(b.x, xv.x, fmaf(b.y, xv.y, fmaf(b.z, xv.z, fmaf(b.w, xv.w, acc1[r]))));
    }
  }
  __syncthreads();
#pragma unroll
  for (int r = 0; r < 8; ++r) { xs[r * 512 + t] = acc0[r]; xs[r * 512 + t + 256] = acc1[r]; }
  __syncthreads();
  int rh = t >> 2, sub = t & 3;
  int row = rh >> 3, head = rh & 7;
  int lat = lat0 + row, pos = SEQ_LEN + lat;
  int bh = batch * 8 + head;
  u16* qd = qws + ((size_t)bh * LAT + lat) * DH;
#pragma unroll
  for (int u = 0; u < 8; ++u) {
    int i = sub * 8 + u;
    float v1 = xs[row * 512 + head * 64 + i];
    float v2 = xs[row * 512 + head * 64 + i + 32];
    float cc = ctab[pos * 32 + i], ss = stab[pos * 32 + i];
    qd[i]      = f2bf((v1 * cc - v2 * ss) * 0.125f);
    qd[i + 32] = f2bf((v2 * cc + v1 * ss) * 0.125f);
  }
}

// ---------------- kernel 2: kv = xbf @ wbf^T (bf16 MFMA, m97 structure) ----------------
// 1-D grid 4128, XCD-swizzled; n fastest (4 n-blocks per m-panel stay on one XCD -> A L2-local).
// 128x128 tile, BK=64, 4 waves (2x2), global_load_lds(16B) staging, linear LDS, 2-barrier loop.
// Epilogue: rope + LN stats per (row, head), store bf16 kv + (mu, rstd).
__global__ __launch_bounds__(256) void k_kvgemm(
    const u16* __restrict__ xbf, const u16* __restrict__ wbf,
    const float* __restrict__ ctab, const float* __restrict__ stab,
    u16* __restrict__ kvws, float2* __restrict__ stats) {
  __shared__ __align__(16) char smem[67584];   // As 16K | Bs 16K ; reused as Cs[128][132] f32
  u16* As = (u16*)smem;                        // [128][64] bf16, linear (global_load_lds dest)
  u16* Bs = (u16*)(smem + 16384);
  float* Cs = (float*)smem;
  int t = threadIdx.x;
  int lane = t & 63, w = t >> 6;
  int wr = w >> 1, wc = w & 1;
  int c = lane & 15, g = lane >> 4;
  // bijective XCD swizzle: 4128 = 8 * 516
  int s = (blockIdx.x & 7) * 516 + (blockIdx.x >> 3);
  int n0 = (s & 3) * 128;
  size_t m0 = (size_t)(s >> 2) * 128;

  f32x4 acc[4][4];
#pragma unroll
  for (int mt = 0; mt < 4; ++mt)
#pragma unroll
    for (int nt = 0; nt < 4; ++nt) acc[mt][nt] = (f32x4){0.f, 0.f, 0.f, 0.f};

  // staging addresses: LDS linear offset o = u*4096 + t*16 bytes; row = o>>7, colb = o&127
  int tr = t >> 3;               // 0..31 (row within 32-row chunk)
  int tcb = (t & 7) * 16;        // byte col within 128B row
  const char* agsrc = (const char*)(xbf + (m0 + tr) * DIM) + tcb;
  const char* bgsrc = (const char*)(wbf + (size_t)(n0 + tr) * DIM) + tcb;
  char* aldst = (char*)As + t * 16;
  char* bldst = (char*)Bs + t * 16;

  for (int kt = 0; kt < 8; ++kt) {
    __syncthreads();                           // prior MFMA reads of LDS done
    {
      const char* ag = agsrc + kt * 128;       // advance 64 bf16 in K
      const char* bg = bgsrc + kt * 128;
#pragma unroll
      for (int u = 0; u < 4; ++u) {            // 32 rows per issue; row stride 1024B
        gload_lds16(ag + (size_t)u * 32 * 1024, aldst + u * 4096);
        gload_lds16(bg + (size_t)u * 32 * 1024, bldst + u * 4096);
      }
    }
    __syncthreads();                           // vmcnt(0) drain inserted by compiler
#pragma unroll
    for (int ks = 0; ks < 2; ++ks) {
      short8 am[4], bn[4];
#pragma unroll
      for (int mt = 0; mt < 4; ++mt) {
        int row = wr * 64 + mt * 16 + c;
        am[mt] = *(const short8*)((char*)As + row * 128 + ks * 64 + g * 16);
      }
#pragma unroll
      for (int nt = 0; nt < 4; ++nt) {
        int row = wc * 64 + nt * 16 + c;
        bn[nt] = *(const short8*)((char*)Bs + row * 128 + ks * 64 + g * 16);
      }
#pragma unroll
      for (int mt = 0; mt < 4; ++mt)
#pragma unroll
        for (int nt = 0; nt < 4; ++nt)
          acc[mt][nt] = __builtin_amdgcn_mfma_f32_16x16x32_bf16(am[mt], bn[nt], acc[mt][nt], 0, 0, 0);
    }
  }
  __syncthreads();
#pragma unroll
  for (int mt = 0; mt < 4; ++mt)
#pragma unroll
    for (int nt = 0; nt < 4; ++nt)
#pragma unroll
      for (int r = 0; r < 4; ++r)
        Cs[(wr * 64 + mt * 16 + 4 * g + r) * 132 + wc * 64 + nt * 16 + c] = acc[mt][nt][r];
  __syncthreads();
  // epilogue: thread t owns (row r_, head-half hh): rope 64 dims, LN stats, store bf16 + stats
  int r_ = t & 127, hh = t >> 7;
  float v[64];
#pragma unroll
  for (int e = 0; e < 64; ++e) v[e] = Cs[r_ * 132 + hh * 64 + e];
  int mi = (int)(m0 + r_);
  int b = mi / NPOS, pos = mi % NPOS;
  const float* ct = ctab + pos * 32;
  const float* st = stab + pos * 32;
#pragma unroll
  for (int i = 0; i < 32; ++i) {
    float cc = ct[i], ss = st[i];
    float v1 = v[i], v2 = v[i + 32];
    v[i]      = v1 * cc - v2 * ss;
    v[i + 32] = v2 * cc + v1 * ss;
  }
  float sum = 0.f;
#pragma unroll
  for (int e = 0; e < 64; ++e) sum += v[e];
  float mu = sum * 0.015625f;
  float sq = 0.f;
#pragma unroll
  for (int e = 0; e < 64; ++e) { float d = v[e] - mu; sq = fmaf(d, d, sq); }
  float rstd = rsqrtf(sq * 0.015625f + 1e-5f);
  int head = (n0 >> 6) + hh;
  int bh = b * 8 + head;
  u32 pk[32];
#pragma unroll
  for (int e = 0; e < 32; ++e) pk[e] = (u32)f2bf(v[2 * e]) | ((u32)f2bf(v[2 * e + 1]) << 16);
  uint4* dst = (uint4*)(kvws + ((size_t)bh * NPOS + pos) * DH);
#pragma unroll
  for (int u = 0; u < 8; ++u) dst[u] = make_uint4(pk[4 * u], pk[4 * u + 1], pk[4 * u + 2], pk[4 * u + 3]);
  stats[(size_t)bh * NPOS + pos] = make_float2(mu, rstd);
}

// ---------------- kernel 3: flash attention over j, split into 4 chunks ----------------
__global__ __launch_bounds__(256) void k_attn(
    const u16* __restrict__ qws, const u16* __restrict__ kvws,
    const float2* __restrict__ stats, const float* __restrict__ lng, const float* __restrict__ lnb,
    float* __restrict__ pout, float* __restrict__ pml) {
  __shared__ __align__(16) u16 LT[64 * 64];        // lkv^T [dd][j], rows XOR-swizzled
  __shared__ __align__(16) u16 Pl[4][16 * 64];     // per-wave P [i][j], XOR-swizzled
  __shared__ float gl[64], bl[64];
  int t = threadIdx.x;
  int lane = t & 63, w = t >> 6;
  int c = lane & 15, g = lane >> 4;
  int bh = blockIdx.y, chunk = blockIdx.x;
  int tt0 = chunk * 33;
  int tt1 = tt0 + 33; if (tt1 > NTILES) tt1 = NTILES;
  if (t < 64) { gl[t] = lng[t]; bl[t] = lnb[t]; }
  short8 qa[2];
  {
    const u16* qrow = qws + ((size_t)bh * LAT + w * 16 + c) * DH;
    qa[0] = *(const short8*)(qrow + 8 * g);
    qa[1] = *(const short8*)(qrow + 32 + 8 * g);
  }
  f32x4 oacc[4];
#pragma unroll
  for (int nt = 0; nt < 4; ++nt) oacc[nt] = (f32x4){0.f, 0.f, 0.f, 0.f};
  float m_run[4], l_run[4];
#pragma unroll
  for (int r = 0; r < 4; ++r) { m_run[r] = -INFINITY; l_run[r] = 0.f; }
  int sj = t & 63, sw = t >> 6;
  for (int tt = tt0; tt < tt1; ++tt) {
    int j0 = tt * 64;
    __syncthreads();
    {                                               // stage LN'd kv transposed: LT[dd][j]
      const u16* src = kvws + ((size_t)bh * NPOS + j0 + sj) * DH + 16 * sw;
      short8 v0 = *(const short8*)src;
      short8 v1 = *(const short8*)(src + 8);
      float2 stv = stats[(size_t)bh * NPOS + j0 + sj];
      float A = stv.y, C = -stv.x * stv.y;
      char* ltb = (char*)LT;
#pragma unroll
      for (int e = 0; e < 16; ++e) {
        int dd = 16 * sw + e;
        u16 uv = (u16)((e < 8) ? v0[e] : v1[e - 8]);
        float y = fmaf(bf2f(uv), A, C);
        y = fmaf(y, gl[dd], bl[dd]);
        *(u16*)(ltb + dd * 128 + ((2 * sj) ^ ((dd & 7) << 4))) = f2bf(y);
      }
    }
    __syncthreads();
    f32x4 sacc[4];
#pragma unroll
    for (int jn = 0; jn < 4; ++jn) sacc[jn] = (f32x4){0.f, 0.f, 0.f, 0.f};
    const u16* kb = kvws + ((size_t)bh * NPOS + j0) * DH;
#pragma unroll
    for (int ks = 0; ks < 2; ++ks)
#pragma unroll
      for (int jn = 0; jn < 4; ++jn) {
        short8 kf = *(const short8*)(kb + (size_t)(jn * 16 + c) * DH + ks * 32 + 8 * g);
        sacc[jn] = __builtin_amdgcn_mfma_f32_16x16x32_bf16(qa[ks], kf, sacc[jn], 0, 0, 0);
      }
    char* pb = (char*)Pl[w];
#pragma unroll
    for (int r = 0; r < 4; ++r) {
      float mt0 = fmaxf(fmaxf(sacc[0][r], sacc[1][r]), fmaxf(sacc[2][r], sacc[3][r]));
      mt0 = fmaxf(mt0, __shfl_xor(mt0, 1));
      mt0 = fmaxf(mt0, __shfl_xor(mt0, 2));
      mt0 = fmaxf(mt0, __shfl_xor(mt0, 4));
      mt0 = fmaxf(mt0, __shfl_xor(mt0, 8));
      float mnew = fmaxf(m_run[r], mt0);
      float corr = __expf(m_run[r] - mnew);
      m_run[r] = mnew;
      float ts = 0.f;
#pragma unroll
      for (int jn = 0; jn < 4; ++jn) {
        float p = __expf(sacc[jn][r] - mnew);
        sacc[jn][r] = p;
        ts += p;
      }
      ts += __shfl_xor(ts, 1); ts += __shfl_xor(ts, 2);
      ts += __shfl_xor(ts, 4); ts += __shfl_xor(ts, 8);
      l_run[r] = l_run[r] * corr + ts;
#pragma unroll
      for (int nt = 0; nt < 4; ++nt) oacc[nt][r] *= corr;
      int i = 4 * g + r;
      int isw = (i & 7) << 4;
#pragma unroll
      for (int jn = 0; jn < 4; ++jn) {
        int j = jn * 16 + c;
        *(u16*)(pb + i * 128 + ((2 * j) ^ isw)) = f2bf(sacc[jn][r]);
      }
    }
#pragma unroll
    for (int ks = 0; ks < 2; ++ks) {
      short8 pa = *(const short8*)(pb + c * 128 + ((ks * 64 + 16 * g) ^ ((c & 7) << 4)));
#pragma unroll
      for (int nt = 0; nt < 4; ++nt) {
        int dd = nt * 16 + c;
        short8 lv = *(const short8*)((char*)LT + dd * 128 + ((ks * 64 + 16 * g) ^ ((dd & 7) << 4)));
        oacc[nt] = __builtin_amdgcn_mfma_f32_16x16x32_bf16(pa, lv, oacc[nt], 0, 0, 0);
      }
    }
  }
  size_t ob = (size_t)bh * NCHUNK + chunk;
#pragma unroll
  for (int nt = 0; nt < 4; ++nt)
#pragma unroll
    for (int r = 0; r < 4; ++r) {
      int i = w * 16 + 4 * g + r;
      pout[(ob * 64 + i) * 64 + nt * 16 + c] = oacc[nt][r];
    }
  if (c == 0) {
#pragma unroll
    for (int r = 0; r < 4; ++r) {
      int i = w * 16 + 4 * g + r;
      pml[(ob * 2 + 0) * 64 + i] = m_run[r];
      pml[(ob * 2 + 1) * 64 + i] = l_run[r];
    }
  }
}

// ---------------- kernel 4: combine split-k partials, normalize, permute to output ----------------
__global__ __launch_bounds__(256) void k_combine(
    const float* __restrict__ pout, const float* __restrict__ pml, float* __restrict__ out) {
  int bh = blockIdx.x, t = threadIdx.x;
  int i = t >> 2, dq = t & 3;
  float mv[NCHUNK], lv[NCHUNK];
#pragma unroll
  for (int cc = 0; cc < NCHUNK; ++cc) {
    size_t ob = (size_t)bh * NCHUNK + cc;
    mv[cc] = pml[(ob * 2 + 0) * 64 + i];
    lv[cc] = pml[(ob * 2 + 1) * 64 + i];
  }
  float M = fmaxf(fmaxf(mv[0], mv[1]), fmaxf(mv[2], mv[3]));
  float wsum = 0.f, wcf[NCHUNK];
#pragma unroll
  for (int cc = 0; cc < NCHUNK; ++cc) { wcf[cc] = __expf(mv[cc] - M); wsum = fmaf(wcf[cc], lv[cc], wsum); }
  float inv = 1.0f / wsum;
#pragma unroll
  for (int e = 0; e < 16; ++e) {
    int dd = dq * 16 + e;
    float a = 0.f;
#pragma unroll
    for (int cc = 0; cc < NCHUNK; ++cc)
      a = fmaf(wcf[cc], pout[(((size_t)bh * NCHUNK + cc) * 64 + i) * 64 + dd], a);
    out[((size_t)(bh >> 3) * LAT + i) * DIM + (bh & 7) * DH + dd] = a * inv;
  }
}

extern "C" void kernel_launch(void* const* d_in, const int* in_sizes, int n_in,
                              void* d_out, int out_size, void* d_ws, size_t ws_size,
                              hipStream_t stream) {
  const float* x   = (const float*)d_in[0];
  const float* wq  = (const float*)d_in[1];
  const float* wkv = (const float*)d_in[2];
  const float* lng = (const float*)d_in[3];
  const float* lnb = (const float*)d_in[4];
  float* out = (float*)d_out;
  char* ws = (char*)d_ws;
  size_t off = 0;
  auto alloc = [&](size_t bytes) { char* p = ws + off; off += (bytes + 255) & ~(size_t)255; return p; };
  float*  ctab  = (float*)alloc((size_t)NPOS * 32 * 4);                 // 1.06 MB
  float*  stab  = (float*)alloc((size_t)NPOS * 32 * 4);                 // 1.06 MB
  u16*    qws   = (u16*)alloc((size_t)NBH * LAT * DH * 2);              // 1 MB
  u16*    kvws  = (u16*)alloc((size_t)NBH * NPOS * DH * 2);             // 135.3 MB
  float2* stats = (float2*)alloc((size_t)NBH * NPOS * 8);               // 8.45 MB
  float*  pout  = (float*)alloc((size_t)NBH * NCHUNK * 64 * 64 * 4);    // 8.39 MB
  float*  pml   = (float*)alloc((size_t)NBH * NCHUNK * 2 * 64 * 4);     // 0.26 MB
  u16*    xbf   = (u16*)alloc((size_t)NROWS * DIM * 2);                 // 135.3 MB
  u16*    wbf   = (u16*)alloc((size_t)DIM * DIM * 2);                   // 0.53 MB
  (void)in_sizes; (void)n_in; (void)out_size; (void)ws_size;            // total ~292 MB

  hipLaunchKernelGGL(k_rtable, dim3(NPOS * 32 / 256), dim3(256), 0, stream, ctab, stab);
  hipLaunchKernelGGL(k_xcast, dim3(2048), dim3(256), 0, stream, x, wkv, xbf, wbf);
  hipLaunchKernelGGL(k_qproj, dim3(128), dim3(256), 0, stream, x, wq, ctab, stab, qws);
  hipLaunchKernelGGL(k_kvgemm, dim3(4128), dim3(256), 0, stream, xbf, wbf, ctab, stab, kvws, stats);
  hipLaunchKernelGGL(k_attn, dim3(NCHUNK, NBH), dim3(256), 0, stream, qws, kvws, stats, lng, lnb, pout, pml);
  hipLaunchKernelGGL(k_combine, dim3(NBH), dim3(256), 0, stream, pout, pml, out);
}

// Round 3
// 431.257 us; speedup vs baseline: 1.2965x; 1.2332x over previous
//
#include <hip/hip_runtime.h>
#include <hip/hip_bf16.h>
#include <math.h>

#define SEQ_LEN 8192
#define LAT 64
#define NPOS 8256          // SEQ_LEN + LAT
#define NBATCH 16
#define NHEADS 8
#define DH 64
#define DIM 512
#define NBH 128            // NBATCH*NHEADS
#define NROWS 132096       // NBATCH*NPOS
#define NCHUNK 4
#define NTILES 129         // NPOS/64

typedef unsigned short u16;
typedef unsigned int   u32;
using short8 = __attribute__((ext_vector_type(8))) short;  // MFMA bf16 A/B frag
using f32x4  = __attribute__((ext_vector_type(4))) float;  // MFMA C/D frag

static __device__ __forceinline__ float bf2f(u16 u) {
  union { u32 i; float f; } v; v.i = ((u32)u) << 16; return v.f;
}
static __device__ __forceinline__ u16 f2bf(float f) {  // round-to-nearest-even
  union { float f; u32 i; } v; v.f = f;
  u32 x = v.i;
  return (u16)((x + 0x7fffu + ((x >> 16) & 1u)) >> 16);
}
static __device__ __forceinline__ void gload_lds16(const void* g, void* l) {
  __builtin_amdgcn_global_load_lds(
      (const __attribute__((address_space(1))) unsigned int*)g,
      (__attribute__((address_space(3))) unsigned int*)l, 16, 0, 0);
}

// ---------------- kernel 0: rope tables ----------------
__global__ void k_rtable(float* __restrict__ ctab, float* __restrict__ stab) {
  int idx = blockIdx.x * 256 + threadIdx.x;   // NPOS*32 total
  int pos = idx >> 5, i = idx & 31;
  float inv = (float)(1.0 / pow(10000.0, (double)(2 * i) / 64.0));
  float ang = (float)pos * inv;
  ctab[idx] = cosf(ang);
  stab[idx] = sinf(ang);
}

// ---------------- kernel 0b: cast x and wkv to bf16 ----------------
__global__ __launch_bounds__(256) void k_xcast(
    const float* __restrict__ x, const float* __restrict__ wkv,
    u16* __restrict__ xbf, u16* __restrict__ wbf) {
  const size_t NX8 = (size_t)NROWS * DIM / 8;
  const size_t NW8 = (size_t)DIM * DIM / 8;
  size_t total = NX8 + NW8;
  for (size_t i = (size_t)blockIdx.x * 256 + threadIdx.x; i < total;
       i += (size_t)gridDim.x * 256) {
    const float4* src; u32* dst; size_t k;
    if (i < NX8) { src = (const float4*)x;   dst = (u32*)xbf; k = i; }
    else         { src = (const float4*)wkv; dst = (u32*)wbf; k = i - NX8; }
    float4 a = src[2 * k], b = src[2 * k + 1];
    uint4 o;
    o.x = (u32)f2bf(a.x) | ((u32)f2bf(a.y) << 16);
    o.y = (u32)f2bf(a.z) | ((u32)f2bf(a.w) << 16);
    o.z = (u32)f2bf(b.x) | ((u32)f2bf(b.y) << 16);
    o.w = (u32)f2bf(b.z) | ((u32)f2bf(b.w) << 16);
    ((uint4*)dst)[k] = o;
  }
}

// ---------------- kernel 1: q projection (latent rows only) + rope + scale ----------------
__global__ __launch_bounds__(256) void k_qproj(
    const float* __restrict__ x, const float* __restrict__ wq,
    const float* __restrict__ ctab, const float* __restrict__ stab,
    u16* __restrict__ qws) {
  __shared__ __align__(16) float xs[8 * 512];
  int t = threadIdx.x;
  int lr0 = blockIdx.x * 8;
  int batch = lr0 >> 6;
  int lat0 = lr0 & 63;
  for (int u = 0; u < 4; ++u) {
    int e = u * 256 + t;
    int row = e >> 7, c4 = e & 127;
    size_t m = (size_t)batch * NPOS + SEQ_LEN + lat0 + row;
    ((float4*)xs)[e] = ((const float4*)(x + m * DIM))[c4];
  }
  __syncthreads();
  float acc0[8], acc1[8];
#pragma unroll
  for (int r = 0; r < 8; ++r) { acc0[r] = 0.f; acc1[r] = 0.f; }
  const float4* w0 = (const float4*)(wq + (size_t)t * DIM);
  const float4* w1 = (const float4*)(wq + (size_t)(t + 256) * DIM);
  for (int kk = 0; kk < 128; ++kk) {
    float4 a = w0[kk], b = w1[kk];
#pragma unroll
    for (int r = 0; r < 8; ++r) {
      float4 xv = ((const float4*)xs)[r * 128 + kk];
      acc0[r] = fmaf(a.x, xv.x, fmaf(a.y, xv.y, fmaf(a.z, xv.z, fmaf(a.w, xv.w, acc0[r]))));
      acc1[r] = fmaf(b.x, xv.x, fmaf(b.y, xv.y, fmaf(b.z, xv.z, fmaf(b.w, xv.w, acc1[r]))));
    }
  }
  __syncthreads();
#pragma unroll
  for (int r = 0; r < 8; ++r) { xs[r * 512 + t] = acc0[r]; xs[r * 512 + t + 256] = acc1[r]; }
  __syncthreads();
  int rh = t >> 2, sub = t & 3;
  int row = rh >> 3, head = rh & 7;
  int lat = lat0 + row, pos = SEQ_LEN + lat;
  int bh = batch * 8 + head;
  u16* qd = qws + ((size_t)bh * LAT + lat) * DH;
#pragma unroll
  for (int u = 0; u < 8; ++u) {
    int i = sub * 8 + u;
    float v1 = xs[row * 512 + head * 64 + i];
    float v2 = xs[row * 512 + head * 64 + i + 32];
    float cc = ctab[pos * 32 + i], ss = stab[pos * 32 + i];
    qd[i]      = f2bf((v1 * cc - v2 * ss) * 0.125f);
    qd[i + 32] = f2bf((v2 * cc + v1 * ss) * 0.125f);
  }
}

// ---------------- kernel 2: kv = xbf @ wbf^T (bf16 MFMA, m97 + swizzle pair) ----------------
// 128x128 tile, BK=64, 4 waves (2x2). global_load_lds(16B) with PRE-SWIZZLED global source
// (m173/rule-21: linear LDS dest + inverse-swizzled src + XOR-swizzled ds_read).
// LDS 33792B (two-pass f32 C epilogue) -> 3 blocks/CU.
__global__ __launch_bounds__(256) void k_kvgemm(
    const u16* __restrict__ xbf, const u16* __restrict__ wbf,
    const float* __restrict__ ctab, const float* __restrict__ stab,
    u16* __restrict__ kvws, float2* __restrict__ stats) {
  __shared__ __align__(16) char smem[33792];   // As 16K | Bs 16K ; reused as Cs[64][132] f32
  u16* As = (u16*)smem;                        // [128][64] bf16, physically col-swizzled
  u16* Bs = (u16*)(smem + 16384);
  float* Cs = (float*)smem;
  int t = threadIdx.x;
  int lane = t & 63, w = t >> 6;
  int wr = w >> 1, wc = w & 1;
  int c = lane & 15, g = lane >> 4;
  // bijective XCD swizzle: 4128 = 8 * 516; n fastest within m-panel
  int s = (blockIdx.x & 7) * 516 + (blockIdx.x >> 3);
  int n0 = (s & 3) * 128;
  size_t m0 = (size_t)(s >> 2) * 128;

  f32x4 acc[4][4];
#pragma unroll
  for (int mt = 0; mt < 4; ++mt)
#pragma unroll
    for (int nt = 0; nt < 4; ++nt) acc[mt][nt] = (f32x4){0.f, 0.f, 0.f, 0.f};

  // staging: lane t -> LDS physical offset u*4096 + t*16 (row = u*32 + t>>3, colb = (t&7)*16).
  // physical (row, pcb) must hold logical (row, pcb ^ ((row&7)<<4)) -> pre-swizzle global col.
  int tr = t >> 3;                                   // row within 32-row chunk
  int tcs = ((t & 7) ^ (tr & 7)) << 4;               // swizzled source byte-col
  const char* agsrc = (const char*)(xbf + (m0 + tr) * DIM) + tcs;
  const char* bgsrc = (const char*)(wbf + (size_t)(n0 + tr) * DIM) + tcs;
  char* aldst = (char*)As + t * 16;
  char* bldst = (char*)Bs + t * 16;

  for (int kt = 0; kt < 8; ++kt) {
    __syncthreads();
    {
      const char* ag = agsrc + kt * 128;
      const char* bg = bgsrc + kt * 128;
#pragma unroll
      for (int u = 0; u < 4; ++u) {
        gload_lds16(ag + (size_t)u * 32 * 1024, aldst + u * 4096);
        gload_lds16(bg + (size_t)u * 32 * 1024, bldst + u * 4096);
      }
    }
    __syncthreads();
#pragma unroll
    for (int ks = 0; ks < 2; ++ks) {
      short8 am[4], bn[4];
#pragma unroll
      for (int mt = 0; mt < 4; ++mt) {
        int row = wr * 64 + mt * 16 + c;
        am[mt] = *(const short8*)((char*)As + row * 128 + ((ks * 64 + g * 16) ^ ((row & 7) << 4)));
      }
#pragma unroll
      for (int nt = 0; nt < 4; ++nt) {
        int row = wc * 64 + nt * 16 + c;
        bn[nt] = *(const short8*)((char*)Bs + row * 128 + ((ks * 64 + g * 16) ^ ((row & 7) << 4)));
      }
#pragma unroll
      for (int mt = 0; mt < 4; ++mt)
#pragma unroll
        for (int nt = 0; nt < 4; ++nt)
          acc[mt][nt] = __builtin_amdgcn_mfma_f32_16x16x32_bf16(am[mt], bn[nt], acc[mt][nt], 0, 0, 0);
    }
  }
  // two-pass epilogue: pass p writes rows [p*64, p*64+64) via Cs[64][132]
  for (int p = 0; p < 2; ++p) {
    __syncthreads();
    if (wr == p) {
#pragma unroll
      for (int mt = 0; mt < 4; ++mt)
#pragma unroll
        for (int nt = 0; nt < 4; ++nt)
#pragma unroll
          for (int r = 0; r < 4; ++r)
            Cs[(mt * 16 + 4 * g + r) * 132 + wc * 64 + nt * 16 + c] = acc[mt][nt][r];
    }
    __syncthreads();
    if (t < 128) {
      int r_ = t & 63, hh = t >> 6;
      float v[64];
      const float4* crow = (const float4*)(Cs + r_ * 132 + hh * 64);
#pragma unroll
      for (int q = 0; q < 16; ++q) {
        float4 f = crow[q];
        v[4 * q] = f.x; v[4 * q + 1] = f.y; v[4 * q + 2] = f.z; v[4 * q + 3] = f.w;
      }
      int mi = (int)(m0 + p * 64 + r_);
      int b = mi / NPOS, pos = mi % NPOS;
      const float* ct = ctab + pos * 32;
      const float* st = stab + pos * 32;
#pragma unroll
      for (int i = 0; i < 32; ++i) {
        float cc = ct[i], ss = st[i];
        float v1 = v[i], v2 = v[i + 32];
        v[i]      = v1 * cc - v2 * ss;
        v[i + 32] = v2 * cc + v1 * ss;
      }
      float sum = 0.f;
#pragma unroll
      for (int e = 0; e < 64; ++e) sum += v[e];
      float mu = sum * 0.015625f;
      float sq = 0.f;
#pragma unroll
      for (int e = 0; e < 64; ++e) { float d = v[e] - mu; sq = fmaf(d, d, sq); }
      float rstd = rsqrtf(sq * 0.015625f + 1e-5f);
      int head = (n0 >> 6) + hh;
      int bh = b * 8 + head;
      u32 pk[32];
#pragma unroll
      for (int e = 0; e < 32; ++e) pk[e] = (u32)f2bf(v[2 * e]) | ((u32)f2bf(v[2 * e + 1]) << 16);
      uint4* dst = (uint4*)(kvws + ((size_t)bh * NPOS + pos) * DH);
#pragma unroll
      for (int u = 0; u < 8; ++u) dst[u] = make_uint4(pk[4 * u], pk[4 * u + 1], pk[4 * u + 2], pk[4 * u + 3]);
      stats[(size_t)bh * NPOS + pos] = make_float2(mu, rstd);
    }
  }
}

// ---------------- kernel 3: flash attention over j, split into 4 chunks ----------------
__global__ __launch_bounds__(256) void k_attn(
    const u16* __restrict__ qws, const u16* __restrict__ kvws,
    const float2* __restrict__ stats, const float* __restrict__ lng, const float* __restrict__ lnb,
    float* __restrict__ pout, float* __restrict__ pml) {
  __shared__ __align__(16) u16 LT[64 * 64];        // lkv^T [dd][j], rows XOR-swizzled
  __shared__ __align__(16) u16 Pl[4][16 * 64];     // per-wave P [i][j], XOR-swizzled
  __shared__ float gl[64], bl[64];
  int t = threadIdx.x;
  int lane = t & 63, w = t >> 6;
  int c = lane & 15, g = lane >> 4;
  int bh = blockIdx.y, chunk = blockIdx.x;
  int tt0 = chunk * 33;
  int tt1 = tt0 + 33; if (tt1 > NTILES) tt1 = NTILES;
  if (t < 64) { gl[t] = lng[t]; bl[t] = lnb[t]; }
  short8 qa[2];
  {
    const u16* qrow = qws + ((size_t)bh * LAT + w * 16 + c) * DH;
    qa[0] = *(const short8*)(qrow + 8 * g);
    qa[1] = *(const short8*)(qrow + 32 + 8 * g);
  }
  f32x4 oacc[4];
#pragma unroll
  for (int nt = 0; nt < 4; ++nt) oacc[nt] = (f32x4){0.f, 0.f, 0.f, 0.f};
  float m_run[4], l_run[4];
#pragma unroll
  for (int r = 0; r < 4; ++r) { m_run[r] = -INFINITY; l_run[r] = 0.f; }
  int sj = t & 63, sw = t >> 6;
  for (int tt = tt0; tt < tt1; ++tt) {
    int j0 = tt * 64;
    __syncthreads();
    {
      const u16* src = kvws + ((size_t)bh * NPOS + j0 + sj) * DH + 16 * sw;
      short8 v0 = *(const short8*)src;
      short8 v1 = *(const short8*)(src + 8);
      float2 stv = stats[(size_t)bh * NPOS + j0 + sj];
      float A = stv.y, C = -stv.x * stv.y;
      char* ltb = (char*)LT;
#pragma unroll
      for (int e = 0; e < 16; ++e) {
        int dd = 16 * sw + e;
        u16 uv = (u16)((e < 8) ? v0[e] : v1[e - 8]);
        float y = fmaf(bf2f(uv), A, C);
        y = fmaf(y, gl[dd], bl[dd]);
        *(u16*)(ltb + dd * 128 + ((2 * sj) ^ ((dd & 7) << 4))) = f2bf(y);
      }
    }
    __syncthreads();
    f32x4 sacc[4];
#pragma unroll
    for (int jn = 0; jn < 4; ++jn) sacc[jn] = (f32x4){0.f, 0.f, 0.f, 0.f};
    const u16* kb = kvws + ((size_t)bh * NPOS + j0) * DH;
#pragma unroll
    for (int ks = 0; ks < 2; ++ks)
#pragma unroll
      for (int jn = 0; jn < 4; ++jn) {
        short8 kf = *(const short8*)(kb + (size_t)(jn * 16 + c) * DH + ks * 32 + 8 * g);
        sacc[jn] = __builtin_amdgcn_mfma_f32_16x16x32_bf16(qa[ks], kf, sacc[jn], 0, 0, 0);
      }
    char* pb = (char*)Pl[w];
#pragma unroll
    for (int r = 0; r < 4; ++r) {
      float mt0 = fmaxf(fmaxf(sacc[0][r], sacc[1][r]), fmaxf(sacc[2][r], sacc[3][r]));
      mt0 = fmaxf(mt0, __shfl_xor(mt0, 1));
      mt0 = fmaxf(mt0, __shfl_xor(mt0, 2));
      mt0 = fmaxf(mt0, __shfl_xor(mt0, 4));
      mt0 = fmaxf(mt0, __shfl_xor(mt0, 8));
      float mnew = fmaxf(m_run[r], mt0);
      float corr = __expf(m_run[r] - mnew);
      m_run[r] = mnew;
      float ts = 0.f;
#pragma unroll
      for (int jn = 0; jn < 4; ++jn) {
        float p = __expf(sacc[jn][r] - mnew);
        sacc[jn][r] = p;
        ts += p;
      }
      ts += __shfl_xor(ts, 1); ts += __shfl_xor(ts, 2);
      ts += __shfl_xor(ts, 4); ts += __shfl_xor(ts, 8);
      l_run[r] = l_run[r] * corr + ts;
#pragma unroll
      for (int nt = 0; nt < 4; ++nt) oacc[nt][r] *= corr;
      int i = 4 * g + r;
      int isw = (i & 7) << 4;
#pragma unroll
      for (int jn = 0; jn < 4; ++jn) {
        int j = jn * 16 + c;
        *(u16*)(pb + i * 128 + ((2 * j) ^ isw)) = f2bf(sacc[jn][r]);
      }
    }
#pragma unroll
    for (int ks = 0; ks < 2; ++ks) {
      short8 pa = *(const short8*)(pb + c * 128 + ((ks * 64 + 16 * g) ^ ((c & 7) << 4)));
#pragma unroll
      for (int nt = 0; nt < 4; ++nt) {
        int dd = nt * 16 + c;
        short8 lv = *(const short8*)((char*)LT + dd * 128 + ((ks * 64 + 16 * g) ^ ((dd & 7) << 4)));
        oacc[nt] = __builtin_amdgcn_mfma_f32_16x16x32_bf16(pa, lv, oacc[nt], 0, 0, 0);
      }
    }
  }
  size_t ob = (size_t)bh * NCHUNK + chunk;
#pragma unroll
  for (int nt = 0; nt < 4; ++nt)
#pragma unroll
    for (int r = 0; r < 4; ++r) {
      int i = w * 16 + 4 * g + r;
      pout[(ob * 64 + i) * 64 + nt * 16 + c] = oacc[nt][r];
    }
  if (c == 0) {
#pragma unroll
    for (int r = 0; r < 4; ++r) {
      int i = w * 16 + 4 * g + r;
      pml[(ob * 2 + 0) * 64 + i] = m_run[r];
      pml[(ob * 2 + 1) * 64 + i] = l_run[r];
    }
  }
}

// ---------------- kernel 4: combine split-k partials ----------------
__global__ __launch_bounds__(256) void k_combine(
    const float* __restrict__ pout, const float* __restrict__ pml, float* __restrict__ out) {
  int bh = blockIdx.x, t = threadIdx.x;
  int i = t >> 2, dq = t & 3;
  float mv[NCHUNK], lv[NCHUNK];
#pragma unroll
  for (int cc = 0; cc < NCHUNK; ++cc) {
    size_t ob = (size_t)bh * NCHUNK + cc;
    mv[cc] = pml[(ob * 2 + 0) * 64 + i];
    lv[cc] = pml[(ob * 2 + 1) * 64 + i];
  }
  float M = fmaxf(fmaxf(mv[0], mv[1]), fmaxf(mv[2], mv[3]));
  float wsum = 0.f, wcf[NCHUNK];
#pragma unroll
  for (int cc = 0; cc < NCHUNK; ++cc) { wcf[cc] = __expf(mv[cc] - M); wsum = fmaf(wcf[cc], lv[cc], wsum); }
  float inv = 1.0f / wsum;
#pragma unroll
  for (int e = 0; e < 16; ++e) {
    int dd = dq * 16 + e;
    float a = 0.f;
#pragma unroll
    for (int cc = 0; cc < NCHUNK; ++cc)
      a = fmaf(wcf[cc], pout[(((size_t)bh * NCHUNK + cc) * 64 + i) * 64 + dd], a);
    out[((size_t)(bh >> 3) * LAT + i) * DIM + (bh & 7) * DH + dd] = a * inv;
  }
}

extern "C" void kernel_launch(void* const* d_in, const int* in_sizes, int n_in,
                              void* d_out, int out_size, void* d_ws, size_t ws_size,
                              hipStream_t stream) {
  const float* x   = (const float*)d_in[0];
  const float* wq  = (const float*)d_in[1];
  const float* wkv = (const float*)d_in[2];
  const float* lng = (const float*)d_in[3];
  const float* lnb = (const float*)d_in[4];
  float* out = (float*)d_out;
  char* ws = (char*)d_ws;
  size_t off = 0;
  auto alloc = [&](size_t bytes) { char* p = ws + off; off += (bytes + 255) & ~(size_t)255; return p; };
  float*  ctab  = (float*)alloc((size_t)NPOS * 32 * 4);
  float*  stab  = (float*)alloc((size_t)NPOS * 32 * 4);
  u16*    qws   = (u16*)alloc((size_t)NBH * LAT * DH * 2);
  u16*    kvws  = (u16*)alloc((size_t)NBH * NPOS * DH * 2);
  float2* stats = (float2*)alloc((size_t)NBH * NPOS * 8);
  float*  pout  = (float*)alloc((size_t)NBH * NCHUNK * 64 * 64 * 4);
  float*  pml   = (float*)alloc((size_t)NBH * NCHUNK * 2 * 64 * 4);
  u16*    xbf   = (u16*)alloc((size_t)NROWS * DIM * 2);
  u16*    wbf   = (u16*)alloc((size_t)DIM * DIM * 2);
  (void)in_sizes; (void)n_in; (void)out_size; (void)ws_size;

  hipLaunchKernelGGL(k_rtable, dim3(NPOS * 32 / 256), dim3(256), 0, stream, ctab, stab);
  hipLaunchKernelGGL(k_xcast, dim3(2048), dim3(256), 0, stream, x, wkv, xbf, wbf);
  hipLaunchKernelGGL(k_qproj, dim3(128), dim3(256), 0, stream, x, wq, ctab, stab, qws);
  hipLaunchKernelGGL(k_kvgemm, dim3(4128), dim3(256), 0, stream, xbf, wbf, ctab, stab, kvws, stats);
  hipLaunchKernelGGL(k_attn, dim3(NCHUNK, NBH), dim3(256), 0, stream, qws, kvws, stats, lng, lnb, pout, pml);
  hipLaunchKernelGGL(k_combine, dim3(NBH), dim3(256), 0, stream, pout, pml, out);
}

// Round 4
// 393.489 us; speedup vs baseline: 1.4210x; 1.0960x over previous
//
#include <hip/hip_runtime.h>
#include <hip/hip_bf16.h>
#include <math.h>

#define SEQ_LEN 8192
#define LAT 64
#define NPOS 8256          // SEQ_LEN + LAT
#define NBATCH 16
#define NHEADS 8
#define DH 64
#define DIM 512
#define NBH 128            // NBATCH*NHEADS
#define NROWS 132096       // NBATCH*NPOS
#define NCHUNK 4
#define NTILES 129         // NPOS/64

typedef unsigned short u16;
typedef unsigned int   u32;
using short8 = __attribute__((ext_vector_type(8))) short;  // MFMA bf16 A/B frag
using f32x4  = __attribute__((ext_vector_type(4))) float;  // MFMA C/D frag

static __device__ __forceinline__ float bf2f(u16 u) {
  union { u32 i; float f; } v; v.i = ((u32)u) << 16; return v.f;
}
static __device__ __forceinline__ u16 f2bf(float f) {  // round-to-nearest-even
  union { float f; u32 i; } v; v.f = f;
  u32 x = v.i;
  return (u16)((x + 0x7fffu + ((x >> 16) & 1u)) >> 16);
}
static __device__ __forceinline__ void gload_lds16(const void* g, void* l) {
  __builtin_amdgcn_global_load_lds(
      (const __attribute__((address_space(1))) unsigned int*)g,
      (__attribute__((address_space(3))) unsigned int*)l, 16, 0, 0);
}

// ---------------- kernel 0: rope tables ----------------
__global__ void k_rtable(float* __restrict__ ctab, float* __restrict__ stab) {
  int idx = blockIdx.x * 256 + threadIdx.x;   // NPOS*32 total
  int pos = idx >> 5, i = idx & 31;
  float inv = (float)(1.0 / pow(10000.0, (double)(2 * i) / 64.0));
  float ang = (float)pos * inv;
  ctab[idx] = cosf(ang);
  stab[idx] = sinf(ang);
}

// ---------------- kernel 0b: cast wkv to bf16 (0.5 MB, ~3 us) ----------------
__global__ __launch_bounds__(256) void k_wcast(const float* __restrict__ wkv, u16* __restrict__ wbf) {
  size_t i = (size_t)blockIdx.x * 256 + threadIdx.x;   // DIM*DIM/8 = 32768 iters
  const float4* src = (const float4*)wkv;
  float4 a = src[2 * i], b = src[2 * i + 1];
  uint4 o;
  o.x = (u32)f2bf(a.x) | ((u32)f2bf(a.y) << 16);
  o.y = (u32)f2bf(a.z) | ((u32)f2bf(a.w) << 16);
  o.z = (u32)f2bf(b.x) | ((u32)f2bf(b.y) << 16);
  o.w = (u32)f2bf(b.z) | ((u32)f2bf(b.w) << 16);
  ((uint4*)wbf)[i] = o;
}

// ---------------- kernel 1: q projection (latent rows only) + rope + scale ----------------
__global__ __launch_bounds__(256) void k_qproj(
    const float* __restrict__ x, const float* __restrict__ wq,
    const float* __restrict__ ctab, const float* __restrict__ stab,
    u16* __restrict__ qws) {
  __shared__ __align__(16) float xs[8 * 512];
  int t = threadIdx.x;
  int lr0 = blockIdx.x * 8;
  int batch = lr0 >> 6;
  int lat0 = lr0 & 63;
  for (int u = 0; u < 4; ++u) {
    int e = u * 256 + t;
    int row = e >> 7, c4 = e & 127;
    size_t m = (size_t)batch * NPOS + SEQ_LEN + lat0 + row;
    ((float4*)xs)[e] = ((const float4*)(x + m * DIM))[c4];
  }
  __syncthreads();
  float acc0[8], acc1[8];
#pragma unroll
  for (int r = 0; r < 8; ++r) { acc0[r] = 0.f; acc1[r] = 0.f; }
  const float4* w0 = (const float4*)(wq + (size_t)t * DIM);
  const float4* w1 = (const float4*)(wq + (size_t)(t + 256) * DIM);
  for (int kk = 0; kk < 128; ++kk) {
    float4 a = w0[kk], b = w1[kk];
#pragma unroll
    for (int r = 0; r < 8; ++r) {
      float4 xv = ((const float4*)xs)[r * 128 + kk];
      acc0[r] = fmaf(a.x, xv.x, fmaf(a.y, xv.y, fmaf(a.z, xv.z, fmaf(a.w, xv.w, acc0[r]))));
      acc1[r] = fmaf(b.x, xv.x, fmaf(b.y, xv.y, fmaf(b.z, xv.z, fmaf(b.w, xv.w, acc1[r]))));
    }
  }
  __syncthreads();
#pragma unroll
  for (int r = 0; r < 8; ++r) { xs[r * 512 + t] = acc0[r]; xs[r * 512 + t + 256] = acc1[r]; }
  __syncthreads();
  int rh = t >> 2, sub = t & 3;
  int row = rh >> 3, head = rh & 7;
  int lat = lat0 + row, pos = SEQ_LEN + lat;
  int bh = batch * 8 + head;
  u16* qd = qws + ((size_t)bh * LAT + lat) * DH;
#pragma unroll
  for (int u = 0; u < 8; ++u) {
    int i = sub * 8 + u;
    float v1 = xs[row * 512 + head * 64 + i];
    float v2 = xs[row * 512 + head * 64 + i + 32];
    float cc = ctab[pos * 32 + i], ss = stab[pos * 32 + i];
    qd[i]      = f2bf((v1 * cc - v2 * ss) * 0.125f);
    qd[i + 32] = f2bf((v2 * cc + v1 * ss) * 0.125f);
  }
}

// ---------------- kernel 2: kv = x @ wbf^T, fused f32->bf16 A-staging, 2-phase dbuf ----------------
// 128x128 tile, BK=64, 4 waves (2x2). A: reg-staged from f32 x (cvt in-kernel, swizzled ds_write).
// B: global_load_lds from pre-cast wbf (pre-swizzled source). One barrier per K-step; loads for
// step kt+1 issued before step kt's MFMA (T3 minimum 2-phase). LDS 64KB -> 2 blocks/CU.
__global__ __launch_bounds__(256, 2) void k_kvgemm(
    const float* __restrict__ x, const u16* __restrict__ wbf,
    const float* __restrict__ ctab, const float* __restrict__ stab,
    u16* __restrict__ kvws, float2* __restrict__ stats) {
  __shared__ __align__(16) char smem[65536];   // A0|A1|B0|B1 16KB each; reused as Cs[64][132] f32
  float* Cs = (float*)smem;
  int t = threadIdx.x;
  int lane = t & 63, w = t >> 6;
  int wr = w >> 1, wc = w & 1;
  int c = lane & 15, g = lane >> 4;
  // bijective XCD swizzle: 4128 = 8 * 516; n fastest within m-panel
  int s = (blockIdx.x & 7) * 516 + (blockIdx.x >> 3);
  int n0 = (s & 3) * 128;
  size_t m0 = (size_t)(s >> 2) * 128;

  f32x4 acc[4][4];
#pragma unroll
  for (int mt = 0; mt < 4; ++mt)
#pragma unroll
    for (int nt = 0; nt < 4; ++nt) acc[mt][nt] = (f32x4){0.f, 0.f, 0.f, 0.f};

  // A staging: thread t -> row-in-chunk ar (u*32+ar), 16B-bf16 col chunk ac8.
  int ar = t >> 3, ac8 = t & 7;
  const float* axbase = x + (m0 + ar) * DIM + ac8 * 8;
  int aswz = (ac8 * 16) ^ ((ar & 7) << 4);     // swizzled byte col (row&7 == ar&7 for all u)
  // B staging: linear LDS dest + pre-swizzled global source (rule 21 pair)
  int tcs = ((t & 7) ^ (ar & 7)) << 4;
  const char* bgsrc = (const char*)(wbf + (size_t)(n0 + ar) * DIM) + tcs;

  float4 a0[4], a1[4];
  auto issueA = [&](int kt) {
#pragma unroll
    for (int u = 0; u < 4; ++u) {
      const float* p = axbase + (size_t)u * 32 * DIM + kt * 64;
      a0[u] = *(const float4*)p;
      a1[u] = *(const float4*)(p + 4);
    }
  };
  auto issueB = [&](int kt, char* bbuf) {
    const char* bg = bgsrc + kt * 128;
    char* bl = bbuf + t * 16;
#pragma unroll
    for (int u = 0; u < 4; ++u) gload_lds16(bg + (size_t)u * 32 * 1024, bl + u * 4096);
  };
  auto writeA = [&](char* abuf) {
#pragma unroll
    for (int u = 0; u < 4; ++u) {
      short8 o;
      o[0] = (short)f2bf(a0[u].x); o[1] = (short)f2bf(a0[u].y);
      o[2] = (short)f2bf(a0[u].z); o[3] = (short)f2bf(a0[u].w);
      o[4] = (short)f2bf(a1[u].x); o[5] = (short)f2bf(a1[u].y);
      o[6] = (short)f2bf(a1[u].z); o[7] = (short)f2bf(a1[u].w);
      *(short8*)(abuf + (u * 32 + ar) * 128 + aswz) = o;
    }
  };

  // prologue: stage kt=0 into buf0
  issueA(0);
  issueB(0, smem + 32768);
  writeA(smem);                 // compiler inserts vmcnt waits for a0/a1 use
  __syncthreads();              // drains B gload + A ds_writes

#pragma unroll
  for (int kt = 0; kt < 8; ++kt) {
    char* Acur = smem + (kt & 1) * 16384;
    char* Bcur = smem + 32768 + (kt & 1) * 16384;
    char* Anxt = smem + ((kt & 1) ^ 1) * 16384;
    char* Bnxt = smem + 32768 + ((kt & 1) ^ 1) * 16384;
    if (kt < 7) { issueA(kt + 1); issueB(kt + 1, Bnxt); }
#pragma unroll
    for (int ks = 0; ks < 2; ++ks) {
      short8 am[4], bn[4];
#pragma unroll
      for (int mt = 0; mt < 4; ++mt) {
        int row = wr * 64 + mt * 16 + c;
        am[mt] = *(const short8*)(Acur + row * 128 + ((ks * 64 + g * 16) ^ ((row & 7) << 4)));
      }
#pragma unroll
      for (int nt = 0; nt < 4; ++nt) {
        int row = wc * 64 + nt * 16 + c;
        bn[nt] = *(const short8*)(Bcur + row * 128 + ((ks * 64 + g * 16) ^ ((row & 7) << 4)));
      }
#pragma unroll
      for (int mt = 0; mt < 4; ++mt)
#pragma unroll
        for (int nt = 0; nt < 4; ++nt)
          acc[mt][nt] = __builtin_amdgcn_mfma_f32_16x16x32_bf16(am[mt], bn[nt], acc[mt][nt], 0, 0, 0);
    }
    if (kt < 7) writeA(Anxt);
    __syncthreads();
  }

  // two-pass epilogue: pass p handles rows [p*64, p*64+64) via Cs[64][132] f32
  for (int p = 0; p < 2; ++p) {
    __syncthreads();
    if (wr == p) {
#pragma unroll
      for (int mt = 0; mt < 4; ++mt)
#pragma unroll
        for (int nt = 0; nt < 4; ++nt)
#pragma unroll
          for (int r = 0; r < 4; ++r)
            Cs[(mt * 16 + 4 * g + r) * 132 + wc * 64 + nt * 16 + c] = acc[mt][nt][r];
    }
    __syncthreads();
    if (t < 128) {
      int r_ = t & 63, hh = t >> 6;
      float v[64];
      const float4* crow = (const float4*)(Cs + r_ * 132 + hh * 64);
#pragma unroll
      for (int q = 0; q < 16; ++q) {
        float4 f = crow[q];
        v[4 * q] = f.x; v[4 * q + 1] = f.y; v[4 * q + 2] = f.z; v[4 * q + 3] = f.w;
      }
      int mi = (int)(m0 + p * 64 + r_);
      int b = mi / NPOS, pos = mi % NPOS;
      const float* ct = ctab + pos * 32;
      const float* st = stab + pos * 32;
#pragma unroll
      for (int i = 0; i < 32; ++i) {
        float cc = ct[i], ss = st[i];
        float v1 = v[i], v2 = v[i + 32];
        v[i]      = v1 * cc - v2 * ss;
        v[i + 32] = v2 * cc + v1 * ss;
      }
      float sum = 0.f;
#pragma unroll
      for (int e = 0; e < 64; ++e) sum += v[e];
      float mu = sum * 0.015625f;
      float sq = 0.f;
#pragma unroll
      for (int e = 0; e < 64; ++e) { float d = v[e] - mu; sq = fmaf(d, d, sq); }
      float rstd = rsqrtf(sq * 0.015625f + 1e-5f);
      int head = (n0 >> 6) + hh;
      int bh = b * 8 + head;
      u32 pk[32];
#pragma unroll
      for (int e = 0; e < 32; ++e) pk[e] = (u32)f2bf(v[2 * e]) | ((u32)f2bf(v[2 * e + 1]) << 16);
      uint4* dst = (uint4*)(kvws + ((size_t)bh * NPOS + pos) * DH);
#pragma unroll
      for (int u = 0; u < 8; ++u) dst[u] = make_uint4(pk[4 * u], pk[4 * u + 1], pk[4 * u + 2], pk[4 * u + 3]);
      stats[(size_t)bh * NPOS + pos] = make_float2(mu, rstd);
    }
  }
}

// ---------------- kernel 3: flash attention over j, split into 4 chunks ----------------
__global__ __launch_bounds__(256) void k_attn(
    const u16* __restrict__ qws, const u16* __restrict__ kvws,
    const float2* __restrict__ stats, const float* __restrict__ lng, const float* __restrict__ lnb,
    float* __restrict__ pout, float* __restrict__ pml) {
  __shared__ __align__(16) u16 LT[64 * 64];        // lkv^T [dd][j], rows XOR-swizzled
  __shared__ __align__(16) u16 Pl[4][16 * 64];     // per-wave P [i][j], XOR-swizzled
  __shared__ float gl[64], bl[64];
  int t = threadIdx.x;
  int lane = t & 63, w = t >> 6;
  int c = lane & 15, g = lane >> 4;
  int bh = blockIdx.y, chunk = blockIdx.x;
  int tt0 = chunk * 33;
  int tt1 = tt0 + 33; if (tt1 > NTILES) tt1 = NTILES;
  if (t < 64) { gl[t] = lng[t]; bl[t] = lnb[t]; }
  short8 qa[2];
  {
    const u16* qrow = qws + ((size_t)bh * LAT + w * 16 + c) * DH;
    qa[0] = *(const short8*)(qrow + 8 * g);
    qa[1] = *(const short8*)(qrow + 32 + 8 * g);
  }
  f32x4 oacc[4];
#pragma unroll
  for (int nt = 0; nt < 4; ++nt) oacc[nt] = (f32x4){0.f, 0.f, 0.f, 0.f};
  float m_run[4], l_run[4];
#pragma unroll
  for (int r = 0; r < 4; ++r) { m_run[r] = -INFINITY; l_run[r] = 0.f; }
  int sj = t & 63, sw = t >> 6;
  for (int tt = tt0; tt < tt1; ++tt) {
    int j0 = tt * 64;
    __syncthreads();
    {
      const u16* src = kvws + ((size_t)bh * NPOS + j0 + sj) * DH + 16 * sw;
      short8 v0 = *(const short8*)src;
      short8 v1 = *(const short8*)(src + 8);
      float2 stv = stats[(size_t)bh * NPOS + j0 + sj];
      float A = stv.y, C = -stv.x * stv.y;
      char* ltb = (char*)LT;
#pragma unroll
      for (int e = 0; e < 16; ++e) {
        int dd = 16 * sw + e;
        u16 uv = (u16)((e < 8) ? v0[e] : v1[e - 8]);
        float y = fmaf(bf2f(uv), A, C);
        y = fmaf(y, gl[dd], bl[dd]);
        *(u16*)(ltb + dd * 128 + ((2 * sj) ^ ((dd & 7) << 4))) = f2bf(y);
      }
    }
    __syncthreads();
    f32x4 sacc[4];
#pragma unroll
    for (int jn = 0; jn < 4; ++jn) sacc[jn] = (f32x4){0.f, 0.f, 0.f, 0.f};
    const u16* kb = kvws + ((size_t)bh * NPOS + j0) * DH;
#pragma unroll
    for (int ks = 0; ks < 2; ++ks)
#pragma unroll
      for (int jn = 0; jn < 4; ++jn) {
        short8 kf = *(const short8*)(kb + (size_t)(jn * 16 + c) * DH + ks * 32 + 8 * g);
        sacc[jn] = __builtin_amdgcn_mfma_f32_16x16x32_bf16(qa[ks], kf, sacc[jn], 0, 0, 0);
      }
    char* pb = (char*)Pl[w];
#pragma unroll
    for (int r = 0; r < 4; ++r) {
      float mt0 = fmaxf(fmaxf(sacc[0][r], sacc[1][r]), fmaxf(sacc[2][r], sacc[3][r]));
      mt0 = fmaxf(mt0, __shfl_xor(mt0, 1));
      mt0 = fmaxf(mt0, __shfl_xor(mt0, 2));
      mt0 = fmaxf(mt0, __shfl_xor(mt0, 4));
      mt0 = fmaxf(mt0, __shfl_xor(mt0, 8));
      float mnew = fmaxf(m_run[r], mt0);
      float corr = __expf(m_run[r] - mnew);
      m_run[r] = mnew;
      float ts = 0.f;
#pragma unroll
      for (int jn = 0; jn < 4; ++jn) {
        float p = __expf(sacc[jn][r] - mnew);
        sacc[jn][r] = p;
        ts += p;
      }
      ts += __shfl_xor(ts, 1); ts += __shfl_xor(ts, 2);
      ts += __shfl_xor(ts, 4); ts += __shfl_xor(ts, 8);
      l_run[r] = l_run[r] * corr + ts;
#pragma unroll
      for (int nt = 0; nt < 4; ++nt) oacc[nt][r] *= corr;
      int i = 4 * g + r;
      int isw = (i & 7) << 4;
#pragma unroll
      for (int jn = 0; jn < 4; ++jn) {
        int j = jn * 16 + c;
        *(u16*)(pb + i * 128 + ((2 * j) ^ isw)) = f2bf(sacc[jn][r]);
      }
    }
#pragma unroll
    for (int ks = 0; ks < 2; ++ks) {
      short8 pa = *(const short8*)(pb + c * 128 + ((ks * 64 + 16 * g) ^ ((c & 7) << 4)));
#pragma unroll
      for (int nt = 0; nt < 4; ++nt) {
        int dd = nt * 16 + c;
        short8 lv = *(const short8*)((char*)LT + dd * 128 + ((ks * 64 + 16 * g) ^ ((dd & 7) << 4)));
        oacc[nt] = __builtin_amdgcn_mfma_f32_16x16x32_bf16(pa, lv, oacc[nt], 0, 0, 0);
      }
    }
  }
  size_t ob = (size_t)bh * NCHUNK + chunk;
#pragma unroll
  for (int nt = 0; nt < 4; ++nt)
#pragma unroll
    for (int r = 0; r < 4; ++r) {
      int i = w * 16 + 4 * g + r;
      pout[(ob * 64 + i) * 64 + nt * 16 + c] = oacc[nt][r];
    }
  if (c == 0) {
#pragma unroll
    for (int r = 0; r < 4; ++r) {
      int i = w * 16 + 4 * g + r;
      pml[(ob * 2 + 0) * 64 + i] = m_run[r];
      pml[(ob * 2 + 1) * 64 + i] = l_run[r];
    }
  }
}

// ---------------- kernel 4: combine split-k partials ----------------
__global__ __launch_bounds__(256) void k_combine(
    const float* __restrict__ pout, const float* __restrict__ pml, float* __restrict__ out) {
  int bh = blockIdx.x, t = threadIdx.x;
  int i = t >> 2, dq = t & 3;
  float mv[NCHUNK], lv[NCHUNK];
#pragma unroll
  for (int cc = 0; cc < NCHUNK; ++cc) {
    size_t ob = (size_t)bh * NCHUNK + cc;
    mv[cc] = pml[(ob * 2 + 0) * 64 + i];
    lv[cc] = pml[(ob * 2 + 1) * 64 + i];
  }
  float M = fmaxf(fmaxf(mv[0], mv[1]), fmaxf(mv[2], mv[3]));
  float wsum = 0.f, wcf[NCHUNK];
#pragma unroll
  for (int cc = 0; cc < NCHUNK; ++cc) { wcf[cc] = __expf(mv[cc] - M); wsum = fmaf(wcf[cc], lv[cc], wsum); }
  float inv = 1.0f / wsum;
#pragma unroll
  for (int e = 0; e < 16; ++e) {
    int dd = dq * 16 + e;
    float a = 0.f;
#pragma unroll
    for (int cc = 0; cc < NCHUNK; ++cc)
      a = fmaf(wcf[cc], pout[(((size_t)bh * NCHUNK + cc) * 64 + i) * 64 + dd], a);
    out[((size_t)(bh >> 3) * LAT + i) * DIM + (bh & 7) * DH + dd] = a * inv;
  }
}

extern "C" void kernel_launch(void* const* d_in, const int* in_sizes, int n_in,
                              void* d_out, int out_size, void* d_ws, size_t ws_size,
                              hipStream_t stream) {
  const float* x   = (const float*)d_in[0];
  const float* wq  = (const float*)d_in[1];
  const float* wkv = (const float*)d_in[2];
  const float* lng = (const float*)d_in[3];
  const float* lnb = (const float*)d_in[4];
  float* out = (float*)d_out;
  char* ws = (char*)d_ws;
  size_t off = 0;
  auto alloc = [&](size_t bytes) { char* p = ws + off; off += (bytes + 255) & ~(size_t)255; return p; };
  float*  ctab  = (float*)alloc((size_t)NPOS * 32 * 4);
  float*  stab  = (float*)alloc((size_t)NPOS * 32 * 4);
  u16*    qws   = (u16*)alloc((size_t)NBH * LAT * DH * 2);
  u16*    kvws  = (u16*)alloc((size_t)NBH * NPOS * DH * 2);
  float2* stats = (float2*)alloc((size_t)NBH * NPOS * 8);
  float*  pout  = (float*)alloc((size_t)NBH * NCHUNK * 64 * 64 * 4);
  float*  pml   = (float*)alloc((size_t)NBH * NCHUNK * 2 * 64 * 4);
  u16*    wbf   = (u16*)alloc((size_t)DIM * DIM * 2);
  (void)in_sizes; (void)n_in; (void)out_size; (void)ws_size;

  hipLaunchKernelGGL(k_rtable, dim3(NPOS * 32 / 256), dim3(256), 0, stream, ctab, stab);
  hipLaunchKernelGGL(k_wcast, dim3(DIM * DIM / 8 / 256), dim3(256), 0, stream, wkv, wbf);
  hipLaunchKernelGGL(k_qproj, dim3(128), dim3(256), 0, stream, x, wq, ctab, stab, qws);
  hipLaunchKernelGGL(k_kvgemm, dim3(4128), dim3(256), 0, stream, x, wbf, ctab, stab, kvws, stats);
  hipLaunchKernelGGL(k_attn, dim3(NCHUNK, NBH), dim3(256), 0, stream, qws, kvws, stats, lng, lnb, pout, pml);
  hipLaunchKernelGGL(k_combine, dim3(NBH), dim3(256), 0, stream, pout, pml, out);
}